// Round 5
// baseline (1334.600 us; speedup 1.0000x reference)
//
#include <hip/hip_runtime.h>
#include <hip/hip_bf16.h>

typedef unsigned short u16;
typedef short bf16x8 __attribute__((ext_vector_type(8)));
typedef float f32x4 __attribute__((ext_vector_type(4)));
typedef unsigned short u16x8 __attribute__((ext_vector_type(8)));

#define PD 147

static const long OFF_PREAL = 134217728L;
static const long OFF_PRECON= 135421952L;
static const long OFF_WA    = 136626176L;
static const long OFF_WP    = 138723328L;

__device__ __forceinline__ float lrelu(float v){ return v >= 0.f ? v : 0.01f*v; }

__device__ __forceinline__ float bf2f(u16 u){
    union { unsigned int i; float f; } x; x.i = ((unsigned int)u) << 16; return x.f;
}
__device__ __forceinline__ u16 f2bf(float f){
    __hip_bfloat16 h = __float2bfloat16(f);
    return *reinterpret_cast<u16*>(&h);
}

__device__ __forceinline__ void gload16(const void* g, void* l){
    __builtin_amdgcn_global_load_lds((const __attribute__((address_space(1))) void*)g,
                                     (__attribute__((address_space(3))) void*)l, 16, 0, 0);
}

// counted vmcnt wait (immediate must be a literal -> small switch, wave-uniform n)
__device__ __forceinline__ void waitv(int n){
    switch(n){
    case 0: asm volatile("s_waitcnt vmcnt(0)" ::: "memory"); break;
    case 1: asm volatile("s_waitcnt vmcnt(1)" ::: "memory"); break;
    case 2: asm volatile("s_waitcnt vmcnt(2)" ::: "memory"); break;
    case 3: asm volatile("s_waitcnt vmcnt(3)" ::: "memory"); break;
    case 4: asm volatile("s_waitcnt vmcnt(4)" ::: "memory"); break;
    case 5: asm volatile("s_waitcnt vmcnt(5)" ::: "memory"); break;
    default: asm volatile("s_waitcnt vmcnt(0)" ::: "memory"); break;
    }
}

// ---------------------------------------------------------------------------
// MFMA implicit-GEMM 3x3 SAME conv.  16x16 spatial tile x all K_OUT channels
// per block.  8 waves (2M x 4N).  Input NHWC bf16 (pre-activated), weights
// pre-transposed [tap][k_out][c_in] bf16.
//
// T3/T4 pipeline: per K-step {issue next-step gload_lds (wave-uniform count)
// -> s_waitcnt vmcnt(N_issued) -> raw s_barrier -> ds_read+MFMA (setprio 1)
// -> raw s_barrier}.  Prefetch stays in flight across the barrier (never
// vmcnt(0) in the main loop).  A/B LDS buffers padded so staging needs no
// q-mask (uniform issue counts); boundary zeros come from the initial LDS
// clear + geometry-masked loads (min-issue N on y-edge blocks is safe:
// vmcnt(N<=J) only over-waits).
// ---------------------------------------------------------------------------
template<int CIN, int KOUT, bool NCHW_OUT>
__global__ __launch_bounds__(512)
void conv_mfma(const u16* __restrict__ fin, const u16* __restrict__ wt,
               void* __restrict__ out_, float* __restrict__ part)
{
    constexpr int CC = CIN / 32;
    constexpr int NSTEPS = CC * 9;
    constexpr int NF = KOUT / 64;
    constexpr int ABUF = 1536 * 16;                   // padded A buffer bytes
    constexpr int ABYTES = 2 * ABUF;
    constexpr int BQ = (KOUT*4 < 512) ? 512 : KOUT*4; // padded quarters per B buffer
    constexpr int NB = BQ / 512;                      // stage_b issues per wave (1 or 2)
    constexpr int BBUF = BQ * 16;
    constexpr int BBYTES = 2 * BBUF;
    constexpr int EPIB = NCHW_OUT ? (8 * 2112 * 4) : (256 * KOUT * 2);
    constexpr int SB = (ABYTES + BBYTES) > EPIB ? (ABYTES + BBYTES) : EPIB;
    __shared__ __align__(16) char smem[SB];
    u16* As = (u16*)smem;
    u16* Bs = (u16*)(smem + ABYTES);

    const int tid = threadIdx.x;
    const int w = tid >> 6, lane = tid & 63;
    const int wm = w >> 2, wn = w & 3;
    const int tile = blockIdx.x;
    const int tx0 = (tile & 15) << 4, ty0 = (tile >> 4) << 4;
    const int b = blockIdx.y;
    const long pixbase = (long)b << 16;
    const int hi = lane >> 4;
    const bool edgey = (ty0 == 0) || (ty0 == 240);

    f32x4 acc[8][NF];
#pragma unroll
    for (int m = 0; m < 8; m++)
#pragma unroll
        for (int n = 0; n < NF; n++) acc[m][n] = (f32x4){0.f,0.f,0.f,0.f};

    // zero both A buffers once (boundary cells rely on staying zero)
    for (int i = tid; i < ABYTES/16; i += 512)
        ((int4*)smem)[i] = make_int4(0,0,0,0);
    __syncthreads();

    auto stage_a = [&](int cc, int buf){
        u16* dstbase = As + buf * (ABUF/2);
#pragma unroll
        for (int r = 0; r < 3; ++r){
            int q = r*512 + w*64 + lane;
            int pf = q >> 2, quarter = q & 3;
            int qs = quarter ^ (pf & 3);            // swizzled source quarter
            int ly = pf / 18;
            int lx = pf - ly*18;
            int gy = ty0 + ly - 1, gx = tx0 + lx - 1;
            bool ok = ((unsigned)gy < 256u) && ((unsigned)gx < 256u);
            const u16* src = fin + ((pixbase + (gy<<8) + gx) * CIN + cc*32 + qs*8);
            u16* dst = dstbase + (r*512 + w*64) * 8;
            if (ok) gload16(src, dst);
        }
    };
    auto stage_b = [&](int cc, int tap, int buf){
        u16* dstbase = Bs + buf * (BBUF/2);
#pragma unroll
        for (int r = 0; r < NB; ++r){
            int q = r*512 + w*64 + lane;
            int k = q >> 2, quarter = q & 3;
            int qs = quarter ^ (k & 3);             // swizzled source quarter
            const u16* src = wt + (((long)tap*KOUT + k) * CIN + cc*32 + qs*8);
            u16* dst = dstbase + (r*512 + w*64) * 8;
            gload16(src, dst);                      // unmasked: buffers padded
        }
    };

    stage_a(0, 0);
    stage_b(0, 0, 0);
    asm volatile("s_waitcnt vmcnt(0)" ::: "memory");
    __syncthreads();

#pragma unroll 1
    for (int step = 0; step < NSTEPS; ++step){
        int cc = step / 9, tap = step - cc*9;
        int nxt = step + 1;
        int nwait = 0;
        if (nxt < NSTEPS){
            int ncc = nxt / 9, ntap = nxt - ncc*9;
            if (ntap == 0){
                stage_a(ncc, ncc & 1);
                stage_b(ncc, ntap, nxt & 1);
                nwait = NB + (edgey ? 2 : 3);
            } else {
                stage_b(ncc, ntap, nxt & 1);
                nwait = NB;
            }
        }
        __builtin_amdgcn_sched_barrier(0);
        waitv(nwait);                    // counted: prefetch stays in flight
        __builtin_amdgcn_s_barrier();    // raw barrier: no implicit vmcnt(0)
        __builtin_amdgcn_sched_barrier(0);

        const u16* Ab = As + (cc & 1) * (ABUF/2);
        const u16* Bb = Bs + (step & 1) * (BBUF/2);
        int dy = tap / 3, dx = tap - dy*3;
        bf16x8 av[8];
#pragma unroll
        for (int m = 0; m < 8; m++){
            int pf = (wm*8 + m + dy)*18 + (lane & 15) + dx;
            av[m] = *(const bf16x8*)(Ab + pf*32 + ((hi ^ (pf & 3)) * 8));
        }
        bf16x8 bv[NF];
#pragma unroll
        for (int n = 0; n < NF; n++){
            int ch = (wn*NF + n)*16 + (lane & 15);
            bv[n] = *(const bf16x8*)(Bb + ch*32 + ((hi ^ (ch & 3)) * 8));
        }
        __builtin_amdgcn_s_setprio(1);
#pragma unroll
        for (int m = 0; m < 8; m++)
#pragma unroll
            for (int n = 0; n < NF; n++)
                acc[m][n] = __builtin_amdgcn_mfma_f32_16x16x32_bf16(av[m], bv[n], acc[m][n], 0, 0, 0);
        __builtin_amdgcn_s_setprio(0);
        __builtin_amdgcn_sched_barrier(0);
        __builtin_amdgcn_s_barrier();    // readers done before next overwrite
    }
    __syncthreads();                      // full drain before epilogue smem reuse

    // ---- fused BN partial stats (fp32, pre-rounding), deterministic slots ----
    {
        const int bid = blockIdx.y * 256 + blockIdx.x;
        const long slot = (long)bid * 2 + wm;
#pragma unroll
        for (int n = 0; n < NF; n++){
            float s = 0.f, s2 = 0.f;
#pragma unroll
            for (int m = 0; m < 8; m++)
#pragma unroll
                for (int j = 0; j < 4; j++){
                    float v = acc[m][n][j];
                    s += v; s2 += v*v;
                }
            s += __shfl_down(s, 32); s2 += __shfl_down(s2, 32);
            s += __shfl_down(s, 16); s2 += __shfl_down(s2, 16);
            if (lane < 16){
                int ch = (wn*NF + n)*16 + lane;
                long off = (slot*KOUT + ch)*2;
                part[off]   = s;
                part[off+1] = s2;
            }
        }
    }

    if constexpr (NCHW_OUT){
        // per-wave LDS transpose -> fp32 NCHW (raw, pre-BN); fully unrolled
        float* ep = (float*)smem + w*2112;
        float* outf = (float*)out_;
#pragma unroll
        for (int nf = 0; nf < NF; ++nf){
#pragma unroll
            for (int m = 0; m < 8; m++)
#pragma unroll
                for (int j = 0; j < 4; j++)
                    ep[(lane&15)*132 + m*16 + (lane>>4)*4 + j] = acc[m][nf][j];
#pragma unroll
            for (int k2 = 0; k2 < 8; k2++){
                int flat = k2*64 + lane;
                int ch = flat >> 5, fmr = (flat>>2)&7, quad = flat & 3;
                float4 v = *(float4*)&ep[ch*132 + fmr*16 + quad*4];
                int cg = wn*(NF*16) + nf*16 + ch;
                long addr = ((long)((b<<8) + cg) << 16) + ((ty0 + wm*8 + fmr) << 8) + tx0 + quad*4;
                *(float4*)(outf + addr) = v;
            }
        }
    } else {
        // block-wide LDS transpose -> NHWC bf16 raw, fully coalesced stores
        u16* ep = (u16*)smem;
        u16* outh = (u16*)out_;
#pragma unroll
        for (int m = 0; m < 8; m++)
#pragma unroll
            for (int n = 0; n < NF; n++){
                int ch = (wn*NF + n)*16 + (lane&15);
#pragma unroll
                for (int j = 0; j < 4; j++){
                    int px = wm*128 + m*16 + (lane>>4)*4 + j;
                    ep[px*KOUT + ch] = f2bf(acc[m][n][j]);
                }
            }
        __syncthreads();
        const int n16 = 256*KOUT/8;
        const int upr = KOUT*2;                 // 16B units per spatial row
        for (int i = tid; i < n16; i += 512){
            int py = i / upr;
            int rem = i - py*upr;
            long ga = (pixbase + ((ty0+py)<<8) + tx0) * KOUT + (long)rem*8;
            *(int4*)(outh + ga) = *(int4*)(ep + (long)i*8);
        }
    }
}

// ---------------------------------------------------------------------------
// conv1: 3->32 direct (tiny), output NHWC bf16 raw
// ---------------------------------------------------------------------------
__global__ __launch_bounds__(256)
void conv1_direct(const float* __restrict__ x, const float* __restrict__ w1, u16* __restrict__ f1)
{
    __shared__ float wl[864];
    const int t = threadIdx.x;
    for (int i = t; i < 864; i += 256) wl[i] = w1[i];
    __syncthreads();
    const int y = blockIdx.x, b = blockIdx.y;
    float acc[32];
#pragma unroll
    for (int k = 0; k < 32; k++) acc[k] = 0.f;
    const long ib = (long)b*3*65536;
    for (int c = 0; c < 3; c++){
#pragma unroll
        for (int dy = 0; dy < 3; dy++){
            int gy = y + dy - 1;
#pragma unroll
            for (int dx = 0; dx < 3; dx++){
                int gx = t + dx - 1;
                float v = 0.f;
                if ((unsigned)gy < 256u && (unsigned)gx < 256u)
                    v = x[ib + c*65536 + (gy<<8) + gx];
                const float* wp = &wl[c*9 + dy*3 + dx];
#pragma unroll
                for (int k = 0; k < 32; k++) acc[k] += v * wp[k*27];
            }
        }
    }
    u16 ub[32];
#pragma unroll
    for (int k = 0; k < 32; k++) ub[k] = f2bf(acc[k]);
    u16* dst = f1 + ((long)(b*65536 + (y<<8) + t)) * 32;
#pragma unroll
    for (int j = 0; j < 4; j++) *(int4*)(dst + j*8) = *(int4*)(ub + j*8);
}

// weight transpose: wt[tap][k][c] = bf16(w[k][c][tap])
__global__ __launch_bounds__(256)
void prep_w(const float* __restrict__ w, u16* __restrict__ wt, int K, int C)
{
    int i = blockIdx.x*256 + threadIdx.x;
    if (i >= 9*K*C) return;
    int c = i % C; int r = i / C; int k = r % K; int tap = r / K;
    wt[i] = f2bf(w[((long)k*C + c)*9 + tap]);
}

// ---------------------------------------------------------------------------
// BN stats over NHWC bf16 (layer 1 only)
// ---------------------------------------------------------------------------
template<int C>
__global__ __launch_bounds__(256)
void bn_stats_nhwc(const u16* __restrict__ f, float* __restrict__ part)
{
    constexpr int CQ = C/4;
    constexpr int SUBS = 256/CQ;
    const int t = threadIdx.x;
    const int cq = t & (CQ-1);
    const int sub = t / CQ;
    const long rowbase = (long)blockIdx.x * 512;
    float s[4] = {0,0,0,0}, q2[4] = {0,0,0,0};
    for (int r = sub; r < 512; r += SUBS){
        ushort4 v = *(const ushort4*)(f + (rowbase + r)*C + cq*4);
        float x0 = bf2f(v.x), x1 = bf2f(v.y), x2 = bf2f(v.z), x3 = bf2f(v.w);
        s[0]+=x0; q2[0]+=x0*x0; s[1]+=x1; q2[1]+=x1*x1;
        s[2]+=x2; q2[2]+=x2*x2; s[3]+=x3; q2[3]+=x3*x3;
    }
    __shared__ float r0[256], r1[256];
    for (int j = 0; j < 4; j++){
        r0[t] = s[j]; r1[t] = q2[j];
        __syncthreads();
        for (int st = 128; st >= CQ; st >>= 1){
            if (t < st){ r0[t] += r0[t+st]; r1[t] += r1[t+st]; }
            __syncthreads();
        }
        if (t < CQ){
            part[((long)blockIdx.x * C + t*4 + j)*2]     = r0[t];
            part[((long)blockIdx.x * C + t*4 + j)*2 + 1] = r1[t];
        }
        __syncthreads();
    }
}

__global__ __launch_bounds__(256)
void bn_stats_final2(const float* __restrict__ part, const float* __restrict__ g,
                     const float* __restrict__ bb, int C, int NB2, float* __restrict__ ss)
{
    const int c = blockIdx.x, t = threadIdx.x;
    float s = 0.f, s2 = 0.f;
    for (int i = t; i < NB2; i += 256){
        s  += part[((long)i*C + c)*2];
        s2 += part[((long)i*C + c)*2 + 1];
    }
    __shared__ float r0[256], r1[256];
    r0[t] = s; r1[t] = s2;
    __syncthreads();
    for (int st = 128; st > 0; st >>= 1){
        if (t < st){ r0[t] += r0[t+st]; r1[t] += r1[t+st]; }
        __syncthreads();
    }
    if (t == 0){
        const float invN = 1.f/524288.f;
        float m = r0[0]*invN;
        float v = r1[0]*invN - m*m;
        float sc = g[c]/sqrtf(v + 1e-5f);
        ss[c] = sc; ss[C+c] = bb[c] - m*sc;
    }
}

// apply BN+lrelu in place on NHWC bf16
template<int C>
__global__ __launch_bounds__(256)
void bn_apply(u16* __restrict__ f, const float* __restrict__ ss, long n8)
{
    long i = (long)blockIdx.x*256 + threadIdx.x;
    if (i >= n8) return;
    u16x8 v = *(u16x8*)(f + i*8);
    int c0 = (int)((i*8) & (C-1));
#pragma unroll
    for (int j = 0; j < 8; j++){
        float xx = bf2f(v[j]);
        xx = lrelu(ss[c0+j]*xx + ss[C+c0+j]);
        v[j] = f2bf(xx);
    }
    *(u16x8*)(f + i*8) = v;
}

// normalize + lrelu layer-4 fp32 NCHW in place
__global__ __launch_bounds__(256)
void bn_finalize(float* __restrict__ feat, const float* __restrict__ ss)
{
    const long e4 = (long)blockIdx.x*256 + threadIdx.x;
    const int c = (int)((e4 >> 14) & 255);
    const float sc = ss[c], sh = ss[256 + c];
    float4 v = reinterpret_cast<float4*>(feat)[e4];
    v.x = lrelu(sc*v.x + sh); v.y = lrelu(sc*v.y + sh);
    v.z = lrelu(sc*v.z + sh); v.w = lrelu(sc*v.w + sh);
    reinterpret_cast<float4*>(feat)[e4] = v;
}

// ---------------------------------------------------------------------------
// gathers + decoder MLP
// ---------------------------------------------------------------------------
__global__ __launch_bounds__(256)
void gather_w(const float* __restrict__ feat, const int* __restrict__ hw,
              float* __restrict__ outW)
{
    const int site = blockIdx.x;
    const int b = site >> 10;
    const int y = hw[site*2], x = hw[site*2 + 1];
    const int c = threadIdx.x;
    const long fidx = (((long)(b*256 + c)) << 16) + ((long)y << 8) + x;
    outW[(long)site*256 + c] = feat[fidx];
}

__global__ __launch_bounds__(256)
void gather_patch(const float* __restrict__ x, const int* __restrict__ hw,
                  float* __restrict__ out)
{
    const long i = (long)blockIdx.x*256 + threadIdx.x;
    if (i >= 1204224L) return;
    const int px = (int)(i % 7);
    long r = i / 7;
    const int py = (int)(r % 7); r /= 7;
    const int c  = (int)(r % 3); r /= 3;
    const int s  = (int)(r % 1024);
    const int b  = (int)(r / 1024);
    const int site = b*1024 + s;
    const int yy = hw[site*2]     - 3 + py;
    const int xx = hw[site*2 + 1] - 3 + px;
    out[i] = x[(((long)(b*3 + c)) << 16) + ((long)yy << 8) + xx];
}

__global__ __launch_bounds__(256)
void mlp(const float* __restrict__ Wa, const float* __restrict__ l1w,
         const float* __restrict__ l1b, const float* __restrict__ l2w,
         const float* __restrict__ l2b, float* __restrict__ out)
{
    __shared__ float wa[256];
    __shared__ float h[160];
    const int site = blockIdx.x;
    const int t = threadIdx.x;
    wa[t] = Wa[(long)site*256 + t];
    __syncthreads();
    if (t < PD){
        float a = l1b[t];
        const float* wr = l1w + t*256;
#pragma unroll 8
        for (int l = 0; l < 256; l++) a += wa[l]*wr[l];
        h[t] = lrelu(a);
    }
    __syncthreads();
    if (t < PD){
        float a = l2b[t];
        const float* wr = l2w + t*PD;
        for (int p = 0; p < PD; p++) a += h[p]*wr[p];
        out[(long)site*PD + t] = a;
    }
}

extern "C" void kernel_launch(void* const* d_in, const int* in_sizes, int n_in,
                              void* d_out, int out_size, void* d_ws, size_t ws_size,
                              hipStream_t stream)
{
    const float* x   = (const float*)d_in[0];
    const int*   anc = (const int*)  d_in[1];
    const int*   pos = (const int*)  d_in[2];
    const float* w1  = (const float*)d_in[3];
    const float* g1  = (const float*)d_in[4];
    const float* b1  = (const float*)d_in[5];
    const float* w2  = (const float*)d_in[6];
    const float* g2  = (const float*)d_in[7];
    const float* b2  = (const float*)d_in[8];
    const float* w3  = (const float*)d_in[9];
    const float* g3  = (const float*)d_in[10];
    const float* b3  = (const float*)d_in[11];
    const float* w4  = (const float*)d_in[12];
    const float* g4  = (const float*)d_in[13];
    const float* b4  = (const float*)d_in[14];
    const float* l1w = (const float*)d_in[15];
    const float* l1b = (const float*)d_in[16];
    const float* l2w = (const float*)d_in[17];
    const float* l2b = (const float*)d_in[18];

    float* feat = (float*)d_out;
    float* oPR  = feat + OFF_PREAL;
    float* oRC  = feat + OFF_PRECON;
    float* oWA  = feat + OFF_WA;
    float* oWP  = feat + OFF_WP;

    // ws: f2 [0,64MB), f3 [64MB,192MB), f1 [128MB,160MB) (inside f3, dead before conv3)
    char* wsb = (char*)d_ws;
    u16* f2b = (u16*)wsb;
    u16* f3b = (u16*)(wsb + 67108864L);
    u16* f1b = (u16*)(wsb + 134217728L);

    // scratch inside d_out regions only written by the final kernels
    u16* Wt2 = (u16*)oWA;
    u16* Wt3 = Wt2 + 18432;
    u16* Wt4 = Wt3 + 73728;
    float* part = oWP;                                   // 4096*256*2 floats max
    float* ss1 = oRC, *ss2 = oRC + 64, *ss3 = oRC + 192, *ss4 = oRC + 448;

    prep_w<<<72,   256, 0, stream>>>(w2, Wt2, 64, 32);
    prep_w<<<288,  256, 0, stream>>>(w3, Wt3, 128, 64);
    prep_w<<<1152, 256, 0, stream>>>(w4, Wt4, 256, 128);

    conv1_direct<<<dim3(256,8), 256, 0, stream>>>(x, w1, f1b);
    bn_stats_nhwc<32><<<1024, 256, 0, stream>>>(f1b, part);
    bn_stats_final2<<<32, 256, 0, stream>>>(part, g1, b1, 32, 1024, ss1);
    bn_apply<32><<<8192, 256, 0, stream>>>(f1b, ss1, 2097152L);

    conv_mfma<32,64,false><<<dim3(256,8), 512, 0, stream>>>(f1b, Wt2, f2b, part);
    bn_stats_final2<<<64, 256, 0, stream>>>(part, g2, b2, 64, 4096, ss2);
    bn_apply<64><<<16384, 256, 0, stream>>>(f2b, ss2, 4194304L);

    conv_mfma<64,128,false><<<dim3(256,8), 512, 0, stream>>>(f2b, Wt3, f3b, part);
    bn_stats_final2<<<128, 256, 0, stream>>>(part, g3, b3, 128, 4096, ss3);
    bn_apply<128><<<32768, 256, 0, stream>>>(f3b, ss3, 8388608L);

    conv_mfma<128,256,true><<<dim3(256,8), 512, 0, stream>>>(f3b, Wt4, feat, part);
    bn_stats_final2<<<256, 256, 0, stream>>>(part, g4, b4, 256, 4096, ss4);
    bn_finalize<<<131072, 256, 0, stream>>>(feat, ss4);

    gather_w<<<8192, 256, 0, stream>>>(feat, anc, oWA);
    gather_w<<<8192, 256, 0, stream>>>(feat, pos, oWP);
    gather_patch<<<4704, 256, 0, stream>>>(x, anc, oPR);
    mlp<<<8192, 256, 0, stream>>>(oWA, l1w, l1b, l2w, l2b, oRC);
}

// Round 6
// 1297.214 us; speedup vs baseline: 1.0288x; 1.0288x over previous
//
#include <hip/hip_runtime.h>
#include <hip/hip_bf16.h>

typedef unsigned short u16;
typedef short bf16x8 __attribute__((ext_vector_type(8)));
typedef float f32x4 __attribute__((ext_vector_type(4)));
typedef unsigned short u16x8 __attribute__((ext_vector_type(8)));

#define PD 147

static const long OFF_PREAL = 134217728L;
static const long OFF_PRECON= 135421952L;
static const long OFF_WA    = 136626176L;
static const long OFF_WP    = 138723328L;

__device__ __forceinline__ float lrelu(float v){ return v >= 0.f ? v : 0.01f*v; }

__device__ __forceinline__ float bf2f(u16 u){
    union { unsigned int i; float f; } x; x.i = ((unsigned int)u) << 16; return x.f;
}
__device__ __forceinline__ u16 f2bf(float f){
    __hip_bfloat16 h = __float2bfloat16(f);
    return *reinterpret_cast<u16*>(&h);
}

__device__ __forceinline__ void gload16(const void* g, void* l){
    __builtin_amdgcn_global_load_lds((const __attribute__((address_space(1))) void*)g,
                                     (__attribute__((address_space(3))) void*)l, 16, 0, 0);
}

// counted vmcnt wait; n is wave-uniform at runtime
__device__ __forceinline__ void waitv(int n){
    switch(n){
    case 0: asm volatile("s_waitcnt vmcnt(0)" ::: "memory"); break;
    case 1: asm volatile("s_waitcnt vmcnt(1)" ::: "memory"); break;
    case 2: asm volatile("s_waitcnt vmcnt(2)" ::: "memory"); break;
    case 3: asm volatile("s_waitcnt vmcnt(3)" ::: "memory"); break;
    case 4: asm volatile("s_waitcnt vmcnt(4)" ::: "memory"); break;
    case 5: asm volatile("s_waitcnt vmcnt(5)" ::: "memory"); break;
    case 6: asm volatile("s_waitcnt vmcnt(6)" ::: "memory"); break;
    case 7: asm volatile("s_waitcnt vmcnt(7)" ::: "memory"); break;
    case 8: asm volatile("s_waitcnt vmcnt(8)" ::: "memory"); break;
    case 9: asm volatile("s_waitcnt vmcnt(9)" ::: "memory"); break;
    case 10: asm volatile("s_waitcnt vmcnt(10)" ::: "memory"); break;
    default: asm volatile("s_waitcnt vmcnt(0)" ::: "memory"); break;
    }
}

// ---------------------------------------------------------------------------
// MFMA implicit-GEMM 3x3 SAME conv.  16x16 spatial tile x all K_OUT channels
// per block.  8 waves (2M x 4N).  Input NHWC bf16 (pre-activated), weights
// pre-transposed [tap][k_out][c_in] bf16.
//
// Depth-3 prefetch pipeline (T3/T4): B is quad-buffered, B(s+3) issued at
// step s; A double-buffered, A(cc+1) issued at tap 6.  Per step:
//   { issue prefetch -> waitcnt vmcnt(N = exact in-flight prefetch count)
//     -> s_barrier -> [sched fence] -> ds_read frags + MFMA -> [fence]
//     -> s_barrier }
// N uses exact per-wave issue counts (wave-uniform); any compiler deviation
// (masked waves still issuing) only lowers N vs reality -> over-wait -> safe.
// Fused deterministic BN partial stats into part[(bid*2+wm)*KOUT + ch].
// ---------------------------------------------------------------------------
template<int CIN, int KOUT, bool NCHW_OUT>
__global__ __launch_bounds__(512)
void conv_mfma(const u16* __restrict__ fin, const u16* __restrict__ wt,
               void* __restrict__ out_, float* __restrict__ part)
{
    constexpr int CC = CIN / 32;
    constexpr int NSTEPS = CC * 9;
    constexpr int NF = KOUT / 64;
    constexpr int NBMAX = (KOUT*4 + 511)/512;         // stage_b loop trips
    constexpr int ABYTES = 2 * 324 * 32 * 2;          // double-buffered 18x18x32 bf16
    constexpr int BBYTES = 4 * KOUT * 32 * 2;         // quad-buffered weights
    constexpr int EPIB = NCHW_OUT ? (8 * 2112 * 4) : (256 * KOUT * 2);
    constexpr int SB = (ABYTES + BBYTES) > EPIB ? (ABYTES + BBYTES) : EPIB;
    __shared__ __align__(16) char smem[SB];
    u16* As = (u16*)smem;
    u16* Bs = (u16*)(smem + ABYTES);

    const int tid = threadIdx.x;
    const int w = tid >> 6, lane = tid & 63;
    const int wm = w >> 2, wn = w & 3;
    const int tile = blockIdx.x;
    const int tx0 = (tile & 15) << 4, ty0 = (tile >> 4) << 4;
    const int b = blockIdx.y;
    const long pixbase = (long)b << 16;
    const int hi = lane >> 4;

    f32x4 acc[8][NF];
#pragma unroll
    for (int m = 0; m < 8; m++)
#pragma unroll
        for (int n = 0; n < NF; n++) acc[m][n] = (f32x4){0.f,0.f,0.f,0.f};

    // zero A buffers once (halo cells are never written -> stay zero)
    for (int i = tid; i < ABYTES/16; i += 512)
        ((int4*)smem)[i] = make_int4(0,0,0,0);
    __syncthreads();

    auto stage_a = [&](int cc, int buf){
        u16* dstbase = As + buf * (324*32);
#pragma unroll
        for (int r = 0; r < 3; ++r){
            int q = r*512 + w*64 + lane;
            int pf = q >> 2, quarter = q & 3;
            int ly = pf / 18;
            int lx = pf - ly*18;
            int gy = ty0 + ly - 1, gx = tx0 + lx - 1;
            bool ok = (q < 1296) && ((unsigned)gy < 256u) && ((unsigned)gx < 256u);
            const u16* src = fin + ((pixbase + (gy<<8) + gx) * CIN + cc*32 + quarter*8);
            u16* dst = dstbase + (r*512 + w*64) * 8;
            if (ok) gload16(src, dst);
        }
    };
    auto stage_b = [&](int s){
        int cc = s / 9, tap = s - cc*9;
        u16* dstbase = Bs + (s & 3) * (KOUT*32);
#pragma unroll
        for (int r = 0; r < NBMAX; ++r){
            int q = r*512 + w*64 + lane;
            int k = q >> 2, quarter = q & 3;
            const u16* src = wt + (((long)tap*KOUT + k) * CIN + cc*32 + quarter*8);
            u16* dst = dstbase + (r*512 + w*64) * 8;
            if (q < KOUT*4) gload16(src, dst);
        }
    };

    // exact per-wave issue counts (wave-uniform)
    int nB = 0;
#pragma unroll
    for (int r = 0; r < NBMAX; r++) if (r*512 + w*64 < KOUT*4) nB++;
    int nA = 0;
    {
        int vlo = (ty0 == 0) ? 1 : 0;
        int vhi = (ty0 == 240) ? 16 : 17;
#pragma unroll
        for (int r = 0; r < 3; r++){
            int pf0 = r*128 + w*16;
            if (pf0 <= 323){
                int pfh = pf0 + 15 > 323 ? 323 : pf0 + 15;
                int lylo = pf0/18, lyhi = pfh/18;
                if (lyhi >= vlo && lylo <= vhi) nA++;
            }
        }
    }

    // prologue: A(0) + B(0..2)
    stage_a(0, 0);
    stage_b(0);
    if (1 < NSTEPS) stage_b(1);
    if (2 < NSTEPS) stage_b(2);

#pragma unroll 1
    for (int s = 0; s < NSTEPS; ++s){
        int cc = s / 9, tap = s - cc*9;
        if (s + 3 < NSTEPS) stage_b(s + 3);
        if (tap == 6 && cc + 1 < CC) stage_a(cc + 1, (cc + 1) & 1);

        int N = 0;
        if (s + 1 < NSTEPS) N += nB;
        if (s + 2 < NSTEPS) N += nB;
        if (s + 3 < NSTEPS) N += nB;
        if (tap >= 6 && cc + 1 < CC) N += nA;

        waitv(N);                        // step-s data resident (this wave)
        __builtin_amdgcn_s_barrier();    // all waves' step-s data resident
        __builtin_amdgcn_sched_barrier(0);  // ds_reads must not hoist above

        const u16* Ab = As + (cc & 1) * (324*32);
        const u16* Bb = Bs + (s & 3) * (KOUT*32);
        int dy = tap / 3, dx = tap - dy*3;
        bf16x8 av[8];
#pragma unroll
        for (int m = 0; m < 8; m++){
            int pf = (wm*8 + m + dy)*18 + (lane & 15) + dx;
            av[m] = *(const bf16x8*)(Ab + pf*32 + hi*8);
        }
        bf16x8 bv[NF];
#pragma unroll
        for (int n = 0; n < NF; n++){
            int ch = (wn*NF + n)*16 + (lane & 15);
            bv[n] = *(const bf16x8*)(Bb + ch*32 + hi*8);
        }
#pragma unroll
        for (int m = 0; m < 8; m++)
#pragma unroll
            for (int n = 0; n < NF; n++)
                acc[m][n] = __builtin_amdgcn_mfma_f32_16x16x32_bf16(av[m], bv[n], acc[m][n], 0, 0, 0);

        __builtin_amdgcn_sched_barrier(0);  // ds_reads must not sink below
        __builtin_amdgcn_s_barrier();       // readers done before buf reuse
    }
    __syncthreads();                         // full drain before epilogue smem reuse

    // ---- fused BN partial stats (fp32, pre-rounding), deterministic slots ----
    {
        const int bid = blockIdx.y * 256 + blockIdx.x;
        const long slot = (long)bid * 2 + wm;
#pragma unroll
        for (int n = 0; n < NF; n++){
            float s = 0.f, s2 = 0.f;
#pragma unroll
            for (int m = 0; m < 8; m++)
#pragma unroll
                for (int j = 0; j < 4; j++){
                    float v = acc[m][n][j];
                    s += v; s2 += v*v;
                }
            s += __shfl_down(s, 32); s2 += __shfl_down(s2, 32);
            s += __shfl_down(s, 16); s2 += __shfl_down(s2, 16);
            if (lane < 16){
                int ch = (wn*NF + n)*16 + lane;
                long off = (slot*KOUT + ch)*2;
                part[off]   = s;
                part[off+1] = s2;
            }
        }
    }

    if constexpr (NCHW_OUT){
        // per-wave LDS transpose -> fp32 NCHW (raw, pre-BN); fully unrolled
        float* ep = (float*)smem + w*2112;
        float* outf = (float*)out_;
#pragma unroll
        for (int nf = 0; nf < NF; ++nf){
#pragma unroll
            for (int m = 0; m < 8; m++)
#pragma unroll
                for (int j = 0; j < 4; j++)
                    ep[(lane&15)*132 + m*16 + (lane>>4)*4 + j] = acc[m][nf][j];
#pragma unroll
            for (int k2 = 0; k2 < 8; k2++){
                int flat = k2*64 + lane;
                int ch = flat >> 5, fmr = (flat>>2)&7, quad = flat & 3;
                float4 v = *(float4*)&ep[ch*132 + fmr*16 + quad*4];
                int cg = wn*(NF*16) + nf*16 + ch;
                long addr = ((long)((b<<8) + cg) << 16) + ((ty0 + wm*8 + fmr) << 8) + tx0 + quad*4;
                *(float4*)(outf + addr) = v;
            }
        }
    } else {
        // block-wide LDS transpose -> NHWC bf16 raw, fully coalesced stores
        u16* ep = (u16*)smem;
        u16* outh = (u16*)out_;
#pragma unroll
        for (int m = 0; m < 8; m++)
#pragma unroll
            for (int n = 0; n < NF; n++){
                int ch = (wn*NF + n)*16 + (lane&15);
#pragma unroll
                for (int j = 0; j < 4; j++){
                    int px = wm*128 + m*16 + (lane>>4)*4 + j;
                    ep[px*KOUT + ch] = f2bf(acc[m][n][j]);
                }
            }
        __syncthreads();
        const int n16 = 256*KOUT/8;
        const int upr = KOUT*2;                 // 16B units per spatial row
        for (int i = tid; i < n16; i += 512){
            int py = i / upr;
            int rem = i - py*upr;
            long ga = (pixbase + ((ty0+py)<<8) + tx0) * KOUT + (long)rem*8;
            *(int4*)(outh + ga) = *(int4*)(ep + (long)i*8);
        }
    }
}

// ---------------------------------------------------------------------------
// conv1: 3->32 direct (tiny), output NHWC bf16 raw
// ---------------------------------------------------------------------------
__global__ __launch_bounds__(256)
void conv1_direct(const float* __restrict__ x, const float* __restrict__ w1, u16* __restrict__ f1)
{
    __shared__ float wl[864];
    const int t = threadIdx.x;
    for (int i = t; i < 864; i += 256) wl[i] = w1[i];
    __syncthreads();
    const int y = blockIdx.x, b = blockIdx.y;
    float acc[32];
#pragma unroll
    for (int k = 0; k < 32; k++) acc[k] = 0.f;
    const long ib = (long)b*3*65536;
    for (int c = 0; c < 3; c++){
#pragma unroll
        for (int dy = 0; dy < 3; dy++){
            int gy = y + dy - 1;
#pragma unroll
            for (int dx = 0; dx < 3; dx++){
                int gx = t + dx - 1;
                float v = 0.f;
                if ((unsigned)gy < 256u && (unsigned)gx < 256u)
                    v = x[ib + c*65536 + (gy<<8) + gx];
                const float* wp = &wl[c*9 + dy*3 + dx];
#pragma unroll
                for (int k = 0; k < 32; k++) acc[k] += v * wp[k*27];
            }
        }
    }
    u16 ub[32];
#pragma unroll
    for (int k = 0; k < 32; k++) ub[k] = f2bf(acc[k]);
    u16* dst = f1 + ((long)(b*65536 + (y<<8) + t)) * 32;
#pragma unroll
    for (int j = 0; j < 4; j++) *(int4*)(dst + j*8) = *(int4*)(ub + j*8);
}

// weight transpose: wt[tap][k][c] = bf16(w[k][c][tap])
__global__ __launch_bounds__(256)
void prep_w(const float* __restrict__ w, u16* __restrict__ wt, int K, int C)
{
    int i = blockIdx.x*256 + threadIdx.x;
    if (i >= 9*K*C) return;
    int c = i % C; int r = i / C; int k = r % K; int tap = r / K;
    wt[i] = f2bf(w[((long)k*C + c)*9 + tap]);
}

// ---------------------------------------------------------------------------
// BN stats over NHWC bf16 (layer 1 only)
// ---------------------------------------------------------------------------
template<int C>
__global__ __launch_bounds__(256)
void bn_stats_nhwc(const u16* __restrict__ f, float* __restrict__ part)
{
    constexpr int CQ = C/4;
    constexpr int SUBS = 256/CQ;
    const int t = threadIdx.x;
    const int cq = t & (CQ-1);
    const int sub = t / CQ;
    const long rowbase = (long)blockIdx.x * 512;
    float s[4] = {0,0,0,0}, q2[4] = {0,0,0,0};
    for (int r = sub; r < 512; r += SUBS){
        ushort4 v = *(const ushort4*)(f + (rowbase + r)*C + cq*4);
        float x0 = bf2f(v.x), x1 = bf2f(v.y), x2 = bf2f(v.z), x3 = bf2f(v.w);
        s[0]+=x0; q2[0]+=x0*x0; s[1]+=x1; q2[1]+=x1*x1;
        s[2]+=x2; q2[2]+=x2*x2; s[3]+=x3; q2[3]+=x3*x3;
    }
    __shared__ float r0[256], r1[256];
    for (int j = 0; j < 4; j++){
        r0[t] = s[j]; r1[t] = q2[j];
        __syncthreads();
        for (int st = 128; st >= CQ; st >>= 1){
            if (t < st){ r0[t] += r0[t+st]; r1[t] += r1[t+st]; }
            __syncthreads();
        }
        if (t < CQ){
            part[((long)blockIdx.x * C + t*4 + j)*2]     = r0[t];
            part[((long)blockIdx.x * C + t*4 + j)*2 + 1] = r1[t];
        }
        __syncthreads();
    }
}

__global__ __launch_bounds__(256)
void bn_stats_final2(const float* __restrict__ part, const float* __restrict__ g,
                     const float* __restrict__ bb, int C, int NB2, float* __restrict__ ss)
{
    const int c = blockIdx.x, t = threadIdx.x;
    float s = 0.f, s2 = 0.f;
    for (int i = t; i < NB2; i += 256){
        s  += part[((long)i*C + c)*2];
        s2 += part[((long)i*C + c)*2 + 1];
    }
    __shared__ float r0[256], r1[256];
    r0[t] = s; r1[t] = s2;
    __syncthreads();
    for (int st = 128; st > 0; st >>= 1){
        if (t < st){ r0[t] += r0[t+st]; r1[t] += r1[t+st]; }
        __syncthreads();
    }
    if (t == 0){
        const float invN = 1.f/524288.f;
        float m = r0[0]*invN;
        float v = r1[0]*invN - m*m;
        float sc = g[c]/sqrtf(v + 1e-5f);
        ss[c] = sc; ss[C+c] = bb[c] - m*sc;
    }
}

// apply BN+lrelu in place on NHWC bf16
template<int C>
__global__ __launch_bounds__(256)
void bn_apply(u16* __restrict__ f, const float* __restrict__ ss, long n8)
{
    long i = (long)blockIdx.x*256 + threadIdx.x;
    if (i >= n8) return;
    u16x8 v = *(u16x8*)(f + i*8);
    int c0 = (int)((i*8) & (C-1));
#pragma unroll
    for (int j = 0; j < 8; j++){
        float xx = bf2f(v[j]);
        xx = lrelu(ss[c0+j]*xx + ss[C+c0+j]);
        v[j] = f2bf(xx);
    }
    *(u16x8*)(f + i*8) = v;
}

// normalize + lrelu layer-4 fp32 NCHW in place
__global__ __launch_bounds__(256)
void bn_finalize(float* __restrict__ feat, const float* __restrict__ ss)
{
    const long e4 = (long)blockIdx.x*256 + threadIdx.x;
    const int c = (int)((e4 >> 14) & 255);
    const float sc = ss[c], sh = ss[256 + c];
    float4 v = reinterpret_cast<float4*>(feat)[e4];
    v.x = lrelu(sc*v.x + sh); v.y = lrelu(sc*v.y + sh);
    v.z = lrelu(sc*v.z + sh); v.w = lrelu(sc*v.w + sh);
    reinterpret_cast<float4*>(feat)[e4] = v;
}

// ---------------------------------------------------------------------------
// gathers + decoder MLP
// ---------------------------------------------------------------------------
__global__ __launch_bounds__(256)
void gather_w(const float* __restrict__ feat, const int* __restrict__ hw,
              float* __restrict__ outW)
{
    const int site = blockIdx.x;
    const int b = site >> 10;
    const int y = hw[site*2], x = hw[site*2 + 1];
    const int c = threadIdx.x;
    const long fidx = (((long)(b*256 + c)) << 16) + ((long)y << 8) + x;
    outW[(long)site*256 + c] = feat[fidx];
}

__global__ __launch_bounds__(256)
void gather_patch(const float* __restrict__ x, const int* __restrict__ hw,
                  float* __restrict__ out)
{
    const long i = (long)blockIdx.x*256 + threadIdx.x;
    if (i >= 1204224L) return;
    const int px = (int)(i % 7);
    long r = i / 7;
    const int py = (int)(r % 7); r /= 7;
    const int c  = (int)(r % 3); r /= 3;
    const int s  = (int)(r % 1024);
    const int b  = (int)(r / 1024);
    const int site = b*1024 + s;
    const int yy = hw[site*2]     - 3 + py;
    const int xx = hw[site*2 + 1] - 3 + px;
    out[i] = x[(((long)(b*3 + c)) << 16) + ((long)yy << 8) + xx];
}

__global__ __launch_bounds__(256)
void mlp(const float* __restrict__ Wa, const float* __restrict__ l1w,
         const float* __restrict__ l1b, const float* __restrict__ l2w,
         const float* __restrict__ l2b, float* __restrict__ out)
{
    __shared__ float wa[256];
    __shared__ float h[160];
    const int site = blockIdx.x;
    const int t = threadIdx.x;
    wa[t] = Wa[(long)site*256 + t];
    __syncthreads();
    if (t < PD){
        float a = l1b[t];
        const float* wr = l1w + t*256;
#pragma unroll 8
        for (int l = 0; l < 256; l++) a += wa[l]*wr[l];
        h[t] = lrelu(a);
    }
    __syncthreads();
    if (t < PD){
        float a = l2b[t];
        const float* wr = l2w + t*PD;
        for (int p = 0; p < PD; p++) a += h[p]*wr[p];
        out[(long)site*PD + t] = a;
    }
}

extern "C" void kernel_launch(void* const* d_in, const int* in_sizes, int n_in,
                              void* d_out, int out_size, void* d_ws, size_t ws_size,
                              hipStream_t stream)
{
    const float* x   = (const float*)d_in[0];
    const int*   anc = (const int*)  d_in[1];
    const int*   pos = (const int*)  d_in[2];
    const float* w1  = (const float*)d_in[3];
    const float* g1  = (const float*)d_in[4];
    const float* b1  = (const float*)d_in[5];
    const float* w2  = (const float*)d_in[6];
    const float* g2  = (const float*)d_in[7];
    const float* b2  = (const float*)d_in[8];
    const float* w3  = (const float*)d_in[9];
    const float* g3  = (const float*)d_in[10];
    const float* b3  = (const float*)d_in[11];
    const float* w4  = (const float*)d_in[12];
    const float* g4  = (const float*)d_in[13];
    const float* b4  = (const float*)d_in[14];
    const float* l1w = (const float*)d_in[15];
    const float* l1b = (const float*)d_in[16];
    const float* l2w = (const float*)d_in[17];
    const float* l2b = (const float*)d_in[18];

    float* feat = (float*)d_out;
    float* oPR  = feat + OFF_PREAL;
    float* oRC  = feat + OFF_PRECON;
    float* oWA  = feat + OFF_WA;
    float* oWP  = feat + OFF_WP;

    // ws: f2 [0,64MB), f3 [64MB,192MB), f1 [128MB,160MB) (inside f3, dead before conv3)
    char* wsb = (char*)d_ws;
    u16* f2b = (u16*)wsb;
    u16* f3b = (u16*)(wsb + 67108864L);
    u16* f1b = (u16*)(wsb + 134217728L);

    // scratch inside d_out regions only written by the final kernels
    u16* Wt2 = (u16*)oWA;
    u16* Wt3 = Wt2 + 18432;
    u16* Wt4 = Wt3 + 73728;
    float* part = oWP;                                   // 4096*256*2 floats max
    float* ss1 = oRC, *ss2 = oRC + 64, *ss3 = oRC + 192, *ss4 = oRC + 448;

    prep_w<<<72,   256, 0, stream>>>(w2, Wt2, 64, 32);
    prep_w<<<288,  256, 0, stream>>>(w3, Wt3, 128, 64);
    prep_w<<<1152, 256, 0, stream>>>(w4, Wt4, 256, 128);

    conv1_direct<<<dim3(256,8), 256, 0, stream>>>(x, w1, f1b);
    bn_stats_nhwc<32><<<1024, 256, 0, stream>>>(f1b, part);
    bn_stats_final2<<<32, 256, 0, stream>>>(part, g1, b1, 32, 1024, ss1);
    bn_apply<32><<<8192, 256, 0, stream>>>(f1b, ss1, 2097152L);

    conv_mfma<32,64,false><<<dim3(256,8), 512, 0, stream>>>(f1b, Wt2, f2b, part);
    bn_stats_final2<<<64, 256, 0, stream>>>(part, g2, b2, 64, 4096, ss2);
    bn_apply<64><<<16384, 256, 0, stream>>>(f2b, ss2, 4194304L);

    conv_mfma<64,128,false><<<dim3(256,8), 512, 0, stream>>>(f2b, Wt3, f3b, part);
    bn_stats_final2<<<128, 256, 0, stream>>>(part, g3, b3, 128, 4096, ss3);
    bn_apply<128><<<32768, 256, 0, stream>>>(f3b, ss3, 8388608L);

    conv_mfma<128,256,true><<<dim3(256,8), 512, 0, stream>>>(f3b, Wt4, feat, part);
    bn_stats_final2<<<256, 256, 0, stream>>>(part, g4, b4, 256, 4096, ss4);
    bn_finalize<<<131072, 256, 0, stream>>>(feat, ss4);

    gather_w<<<8192, 256, 0, stream>>>(feat, anc, oWA);
    gather_w<<<8192, 256, 0, stream>>>(feat, pos, oWP);
    gather_patch<<<4704, 256, 0, stream>>>(x, anc, oPR);
    mlp<<<8192, 256, 0, stream>>>(oWA, l1w, l1b, l2w, l2b, oRC);
}

// Round 8
// 1187.305 us; speedup vs baseline: 1.1241x; 1.0926x over previous
//
#include <hip/hip_runtime.h>
#include <hip/hip_bf16.h>

typedef unsigned short u16;
typedef short bf16x8 __attribute__((ext_vector_type(8)));
typedef float f32x4 __attribute__((ext_vector_type(4)));
typedef unsigned short u16x8 __attribute__((ext_vector_type(8)));

#define PD 147

static const long OFF_PREAL = 134217728L;
static const long OFF_PRECON= 135421952L;
static const long OFF_WA    = 136626176L;
static const long OFF_WP    = 138723328L;

// raw f4 bf16 NCHW split: elems [0,100663296) at d_out u16-offset 167772160
// (= top 201.3MB of feat region), elems [100663296,134217728) in ws f2 region.
static const long RAW_SPLIT = 100663296L;

__device__ __forceinline__ float lrelu(float v){ return v >= 0.f ? v : 0.01f*v; }

__device__ __forceinline__ float bf2f(u16 u){
    union { unsigned int i; float f; } x; x.i = ((unsigned int)u) << 16; return x.f;
}
__device__ __forceinline__ u16 f2bf(float f){
    __hip_bfloat16 h = __float2bfloat16(f);
    return *reinterpret_cast<u16*>(&h);
}

__device__ __forceinline__ void gload16(const void* g, void* l){
    __builtin_amdgcn_global_load_lds((const __attribute__((address_space(1))) void*)g,
                                     (__attribute__((address_space(3))) void*)l, 16, 0, 0);
}

// ---------------------------------------------------------------------------
// MFMA implicit-GEMM 3x3 SAME conv.  16x16 spatial tile x all K_OUT channels
// per block.  8 waves (2M x 4N).  Input NHWC bf16 (pre-activated), weights
// pre-transposed [tap][k_out][c_in] bf16.
//
// BK=96 steps: one step = one dy-row (3 taps), 12 steps for conv4.  Round-4
// proven single-barrier skeleton: stage(next step) -> compute(cur, 3 taps)
// -> __syncthreads (full drain).  3x fewer barrier/drain stalls than BK=32.
//
// CRITICAL (guide §5, m104/m108): gload16's LDS destination must be the
// WAVE-UNIFORM base (HW adds lane*16B).  A per-lane dst + masked exec makes
// readfirstlane pick a shifted base on edge tiles (round-7 bug).
// Fused deterministic BN partial stats.  Output: NHWC bf16 raw, or (conv4)
// NCHW bf16 raw split across rawlo/rawhi.
// ---------------------------------------------------------------------------
template<int CIN, int KOUT, bool NCHW_OUT>
__global__ __launch_bounds__(512)
void conv_mfma(const u16* __restrict__ fin, const u16* __restrict__ wt,
               void* __restrict__ out_, u16* __restrict__ rawhi,
               float* __restrict__ part)
{
    constexpr int CC = CIN / 32;
    constexpr int NS3 = CC * 3;                        // dy-row steps
    constexpr int NF = KOUT / 64;
    constexpr int ABYTES = 2 * 324 * 32 * 2;           // dbuf 18x18x32 bf16
    constexpr int BQ = 3 * KOUT * 4;                   // quarters per B buffer
    constexpr int NB3 = (BQ + 511) / 512;              // stage_b rounds
    constexpr int BBYTES = 2 * BQ * 16;
    constexpr int EPIB = NCHW_OUT ? (8 * 2112 * 4) : (256 * KOUT * 2);
    constexpr int SB = (ABYTES + BBYTES) > EPIB ? (ABYTES + BBYTES) : EPIB;
    __shared__ __align__(16) char smem[SB];
    u16* As = (u16*)smem;
    u16* Bs = (u16*)(smem + ABYTES);

    const int tid = threadIdx.x;
    const int w = tid >> 6, lane = tid & 63;
    const int wm = w >> 2, wn = w & 3;
    const int tile = blockIdx.x;
    const int tx0 = (tile & 15) << 4, ty0 = (tile >> 4) << 4;
    const int b = blockIdx.y;
    const long pixbase = (long)b << 16;
    const int hi = lane >> 4;

    f32x4 acc[8][NF];
#pragma unroll
    for (int m = 0; m < 8; m++)
#pragma unroll
        for (int n = 0; n < NF; n++) acc[m][n] = (f32x4){0.f,0.f,0.f,0.f};

    // zero both A buffers once (halo cells never written -> stay zero)
    for (int i = tid; i < ABYTES/16; i += 512)
        ((int4*)smem)[i] = make_int4(0,0,0,0);
    __syncthreads();

    auto stage_a_round = [&](int cc, int buf, int r){
        u16* dstbase = As + buf * (324*32);
        int q = r*512 + w*64 + lane;
        int pf = q >> 2, quarter = q & 3;
        int ly = pf / 18;
        int lx = pf - ly*18;
        int gy = ty0 + ly - 1, gx = tx0 + lx - 1;
        bool ok = (q < 1296) && ((unsigned)gy < 256u) && ((unsigned)gx < 256u);
        const u16* src = fin + ((pixbase + (gy<<8) + gx) * CIN + cc*32 + quarter*8);
        u16* dst = dstbase + (r*512 + w*64) * 8;   // WAVE-UNIFORM base
        if (ok) gload16(src, dst);
    };
    auto stage_b3 = [&](int s, int buf){
        int cc = s / 3, dyr = s - cc*3;
        int t0 = dyr * 3;
        u16* dstbase = Bs + buf * (BQ*16/2);
#pragma unroll
        for (int r = 0; r < NB3; ++r){
            int q = r*512 + w*64 + lane;
            int tl = q / (KOUT*4);
            int qq = q - tl*(KOUT*4);
            int k = qq >> 2, quarter = qq & 3;
            const u16* src = wt + (((long)(t0+tl)*KOUT + k) * CIN + cc*32 + quarter*8);
            u16* dst = dstbase + (r*512 + w*64) * 8;   // WAVE-UNIFORM base
            if (q < BQ) gload16(src, dst);
        }
    };

    // prologue
    stage_a_round(0, 0, 0); stage_a_round(0, 0, 1); stage_a_round(0, 0, 2);
    stage_b3(0, 0);
    __syncthreads();

#pragma unroll 1
    for (int s = 0; s < NS3; ++s){
        int cc = s / 3, dyr = s - cc*3;
        if (s + 1 < NS3) stage_b3(s + 1, (s + 1) & 1);
        if (cc + 1 < CC) stage_a_round(cc + 1, (cc + 1) & 1, dyr);

        const u16* Ab = As + (cc & 1) * (324*32);
        const u16* Bb = Bs + (s & 1) * (BQ*16/2);
#pragma unroll
        for (int t = 0; t < 3; ++t){
            bf16x8 av[8];
#pragma unroll
            for (int m = 0; m < 8; m++){
                int pf = (wm*8 + m + dyr)*18 + (lane & 15) + t;
                av[m] = *(const bf16x8*)(Ab + pf*32 + hi*8);
            }
            bf16x8 bv[NF];
#pragma unroll
            for (int n = 0; n < NF; n++){
                int ch = (wn*NF + n)*16 + (lane & 15);
                bv[n] = *(const bf16x8*)(Bb + (t*KOUT + ch)*32 + hi*8);
            }
#pragma unroll
            for (int m = 0; m < 8; m++)
#pragma unroll
                for (int n = 0; n < NF; n++)
                    acc[m][n] = __builtin_amdgcn_mfma_f32_16x16x32_bf16(av[m], bv[n], acc[m][n], 0, 0, 0);
        }
        __syncthreads();   // drains vmcnt (next bufs ready) + readers done
    }

    // ---- fused BN partial stats (fp32, pre-rounding), deterministic slots ----
    {
        const int bid = blockIdx.y * 256 + blockIdx.x;
        const long slot = (long)bid * 2 + wm;
#pragma unroll
        for (int n = 0; n < NF; n++){
            float s = 0.f, s2 = 0.f;
#pragma unroll
            for (int m = 0; m < 8; m++)
#pragma unroll
                for (int j = 0; j < 4; j++){
                    float v = acc[m][n][j];
                    s += v; s2 += v*v;
                }
            s += __shfl_down(s, 32); s2 += __shfl_down(s2, 32);
            s += __shfl_down(s, 16); s2 += __shfl_down(s2, 16);
            if (lane < 16){
                int ch = (wn*NF + n)*16 + lane;
                long off = (slot*KOUT + ch)*2;
                part[off]   = s;
                part[off+1] = s2;
            }
        }
    }

    if constexpr (NCHW_OUT){
        // per-wave LDS transpose -> bf16 NCHW raw (pre-BN), split dest
        float* ep = (float*)smem + w*2112;
        u16* rawlo = (u16*)out_;
#pragma unroll
        for (int nf = 0; nf < NF; ++nf){
#pragma unroll
            for (int m = 0; m < 8; m++)
#pragma unroll
                for (int j = 0; j < 4; j++)
                    ep[(lane&15)*132 + m*16 + (lane>>4)*4 + j] = acc[m][nf][j];
#pragma unroll
            for (int k2 = 0; k2 < 8; k2++){
                int flat = k2*64 + lane;
                int ch = flat >> 5, fmr = (flat>>2)&7, quad = flat & 3;
                float4 v = *(float4*)&ep[ch*132 + fmr*16 + quad*4];
                int cg = wn*(NF*16) + nf*16 + ch;
                long addr = ((long)((b<<8) + cg) << 16) + ((ty0 + wm*8 + fmr) << 8) + tx0 + quad*4;
                ushort4 u;
                u.x = f2bf(v.x); u.y = f2bf(v.y); u.z = f2bf(v.z); u.w = f2bf(v.w);
                u16* dst = (addr < RAW_SPLIT) ? (rawlo + addr) : (rawhi + (addr - RAW_SPLIT));
                *(ushort4*)dst = u;
            }
        }
    } else {
        // block-wide LDS transpose -> NHWC bf16 raw, fully coalesced stores
        u16* ep = (u16*)smem;
        u16* outh = (u16*)out_;
#pragma unroll
        for (int m = 0; m < 8; m++)
#pragma unroll
            for (int n = 0; n < NF; n++){
                int ch = (wn*NF + n)*16 + (lane&15);
#pragma unroll
                for (int j = 0; j < 4; j++){
                    int px = wm*128 + m*16 + (lane>>4)*4 + j;
                    ep[px*KOUT + ch] = f2bf(acc[m][n][j]);
                }
            }
        __syncthreads();
        const int n16 = 256*KOUT/8;
        const int upr = KOUT*2;                 // 16B units per spatial row
        for (int i = tid; i < n16; i += 512){
            int py = i / upr;
            int rem = i - py*upr;
            long ga = (pixbase + ((ty0+py)<<8) + tx0) * KOUT + (long)rem*8;
            *(int4*)(outh + ga) = *(int4*)(ep + (long)i*8);
        }
    }
}

// ---------------------------------------------------------------------------
// conv1: 3->32 direct (tiny), output NHWC bf16 raw
// ---------------------------------------------------------------------------
__global__ __launch_bounds__(256)
void conv1_direct(const float* __restrict__ x, const float* __restrict__ w1, u16* __restrict__ f1)
{
    __shared__ float wl[864];
    const int t = threadIdx.x;
    for (int i = t; i < 864; i += 256) wl[i] = w1[i];
    __syncthreads();
    const int y = blockIdx.x, b = blockIdx.y;
    float acc[32];
#pragma unroll
    for (int k = 0; k < 32; k++) acc[k] = 0.f;
    const long ib = (long)b*3*65536;
    for (int c = 0; c < 3; c++){
#pragma unroll
        for (int dy = 0; dy < 3; dy++){
            int gy = y + dy - 1;
#pragma unroll
            for (int dx = 0; dx < 3; dx++){
                int gx = t + dx - 1;
                float v = 0.f;
                if ((unsigned)gy < 256u && (unsigned)gx < 256u)
                    v = x[ib + c*65536 + (gy<<8) + gx];
                const float* wp = &wl[c*9 + dy*3 + dx];
#pragma unroll
                for (int k = 0; k < 32; k++) acc[k] += v * wp[k*27];
            }
        }
    }
    u16 ub[32];
#pragma unroll
    for (int k = 0; k < 32; k++) ub[k] = f2bf(acc[k]);
    u16* dst = f1 + ((long)(b*65536 + (y<<8) + t)) * 32;
#pragma unroll
    for (int j = 0; j < 4; j++) *(int4*)(dst + j*8) = *(int4*)(ub + j*8);
}

// weight transpose: wt[tap][k][c] = bf16(w[k][c][tap])
__global__ __launch_bounds__(256)
void prep_w(const float* __restrict__ w, u16* __restrict__ wt, int K, int C)
{
    int i = blockIdx.x*256 + threadIdx.x;
    if (i >= 9*K*C) return;
    int c = i % C; int r = i / C; int k = r % K; int tap = r / K;
    wt[i] = f2bf(w[((long)k*C + c)*9 + tap]);
}

// ---------------------------------------------------------------------------
// BN stats over NHWC bf16 (layer 1 only)
// ---------------------------------------------------------------------------
template<int C>
__global__ __launch_bounds__(256)
void bn_stats_nhwc(const u16* __restrict__ f, float* __restrict__ part)
{
    constexpr int CQ = C/4;
    constexpr int SUBS = 256/CQ;
    const int t = threadIdx.x;
    const int cq = t & (CQ-1);
    const int sub = t / CQ;
    const long rowbase = (long)blockIdx.x * 512;
    float s[4] = {0,0,0,0}, q2[4] = {0,0,0,0};
    for (int r = sub; r < 512; r += SUBS){
        ushort4 v = *(const ushort4*)(f + (rowbase + r)*C + cq*4);
        float x0 = bf2f(v.x), x1 = bf2f(v.y), x2 = bf2f(v.z), x3 = bf2f(v.w);
        s[0]+=x0; q2[0]+=x0*x0; s[1]+=x1; q2[1]+=x1*x1;
        s[2]+=x2; q2[2]+=x2*x2; s[3]+=x3; q2[3]+=x3*x3;
    }
    __shared__ float r0[256], r1[256];
    for (int j = 0; j < 4; j++){
        r0[t] = s[j]; r1[t] = q2[j];
        __syncthreads();
        for (int st = 128; st >= CQ; st >>= 1){
            if (t < st){ r0[t] += r0[t+st]; r1[t] += r1[t+st]; }
            __syncthreads();
        }
        if (t < CQ){
            part[((long)blockIdx.x * C + t*4 + j)*2]     = r0[t];
            part[((long)blockIdx.x * C + t*4 + j)*2 + 1] = r1[t];
        }
        __syncthreads();
    }
}

__global__ __launch_bounds__(256)
void bn_stats_final2(const float* __restrict__ part, const float* __restrict__ g,
                     const float* __restrict__ bb, int C, int NB2, float* __restrict__ ss)
{
    const int c = blockIdx.x, t = threadIdx.x;
    float s = 0.f, s2 = 0.f;
    for (int i = t; i < NB2; i += 256){
        s  += part[((long)i*C + c)*2];
        s2 += part[((long)i*C + c)*2 + 1];
    }
    __shared__ float r0[256], r1[256];
    r0[t] = s; r1[t] = s2;
    __syncthreads();
    for (int st = 128; st > 0; st >>= 1){
        if (t < st){ r0[t] += r0[t+st]; r1[t] += r1[t+st]; }
        __syncthreads();
    }
    if (t == 0){
        const float invN = 1.f/524288.f;
        float m = r0[0]*invN;
        float v = r1[0]*invN - m*m;
        float sc = g[c]/sqrtf(v + 1e-5f);
        ss[c] = sc; ss[C+c] = bb[c] - m*sc;
    }
}

// apply BN+lrelu in place on NHWC bf16
template<int C>
__global__ __launch_bounds__(256)
void bn_apply(u16* __restrict__ f, const float* __restrict__ ss, long n8)
{
    long i = (long)blockIdx.x*256 + threadIdx.x;
    if (i >= n8) return;
    u16x8 v = *(u16x8*)(f + i*8);
    int c0 = (int)((i*8) & (C-1));
#pragma unroll
    for (int j = 0; j < 8; j++){
        float xx = bf2f(v[j]);
        xx = lrelu(ss[c0+j]*xx + ss[C+c0+j]);
        v[j] = f2bf(xx);
    }
    *(u16x8*)(f + i*8) = v;
}

// ---------------------------------------------------------------------------
// expand raw bf16 NCHW (+BN+lrelu) -> fp32 NCHW feat.  src points at the
// first raw element of this range; i0 = global elem offset; n = elem count.
// Launch order guarantees no write clobbers unread raw (see launch site).
// ---------------------------------------------------------------------------
__global__ __launch_bounds__(256)
void bn_expand(const u16* __restrict__ src, const float* __restrict__ ss,
               float* __restrict__ feat, long i0, long n)
{
    long i8 = (long)blockIdx.x*256 + threadIdx.x;
    if (i8*8 >= n) return;
    long base = i0 + i8*8;
    u16x8 v = *(const u16x8*)(src + i8*8);
    int c = (int)((base >> 16) & 255);
    float sc = ss[c], sh = ss[256 + c];
    float4 o0, o1;
    o0.x = lrelu(sc*bf2f(v[0]) + sh);
    o0.y = lrelu(sc*bf2f(v[1]) + sh);
    o0.z = lrelu(sc*bf2f(v[2]) + sh);
    o0.w = lrelu(sc*bf2f(v[3]) + sh);
    o1.x = lrelu(sc*bf2f(v[4]) + sh);
    o1.y = lrelu(sc*bf2f(v[5]) + sh);
    o1.z = lrelu(sc*bf2f(v[6]) + sh);
    o1.w = lrelu(sc*bf2f(v[7]) + sh);
    *(float4*)(feat + base)     = o0;
    *(float4*)(feat + base + 4) = o1;
}

// ---------------------------------------------------------------------------
// gathers + decoder MLP
// ---------------------------------------------------------------------------
__global__ __launch_bounds__(256)
void gather_w(const float* __restrict__ feat, const int* __restrict__ hw,
              float* __restrict__ outW)
{
    const int site = blockIdx.x;
    const int b = site >> 10;
    const int y = hw[site*2], x = hw[site*2 + 1];
    const int c = threadIdx.x;
    const long fidx = (((long)(b*256 + c)) << 16) + ((long)y << 8) + x;
    outW[(long)site*256 + c] = feat[fidx];
}

__global__ __launch_bounds__(256)
void gather_patch(const float* __restrict__ x, const int* __restrict__ hw,
                  float* __restrict__ out)
{
    const long i = (long)blockIdx.x*256 + threadIdx.x;
    if (i >= 1204224L) return;
    const int px = (int)(i % 7);
    long r = i / 7;
    const int py = (int)(r % 7); r /= 7;
    const int c  = (int)(r % 3); r /= 3;
    const int s  = (int)(r % 1024);
    const int b  = (int)(r / 1024);
    const int site = b*1024 + s;
    const int yy = hw[site*2]     - 3 + py;
    const int xx = hw[site*2 + 1] - 3 + px;
    out[i] = x[(((long)(b*3 + c)) << 16) + ((long)yy << 8) + xx];
}

__global__ __launch_bounds__(256)
void mlp(const float* __restrict__ Wa, const float* __restrict__ l1w,
         const float* __restrict__ l1b, const float* __restrict__ l2w,
         const float* __restrict__ l2b, float* __restrict__ out)
{
    __shared__ float wa[256];
    __shared__ float h[160];
    const int site = blockIdx.x;
    const int t = threadIdx.x;
    wa[t] = Wa[(long)site*256 + t];
    __syncthreads();
    if (t < PD){
        float a = l1b[t];
        const float* wr = l1w + t*256;
#pragma unroll 8
        for (int l = 0; l < 256; l++) a += wa[l]*wr[l];
        h[t] = lrelu(a);
    }
    __syncthreads();
    if (t < PD){
        float a = l2b[t];
        const float* wr = l2w + t*PD;
        for (int p = 0; p < PD; p++) a += h[p]*wr[p];
        out[(long)site*PD + t] = a;
    }
}

extern "C" void kernel_launch(void* const* d_in, const int* in_sizes, int n_in,
                              void* d_out, int out_size, void* d_ws, size_t ws_size,
                              hipStream_t stream)
{
    const float* x   = (const float*)d_in[0];
    const int*   anc = (const int*)  d_in[1];
    const int*   pos = (const int*)  d_in[2];
    const float* w1  = (const float*)d_in[3];
    const float* g1  = (const float*)d_in[4];
    const float* b1  = (const float*)d_in[5];
    const float* w2  = (const float*)d_in[6];
    const float* g2  = (const float*)d_in[7];
    const float* b2  = (const float*)d_in[8];
    const float* w3  = (const float*)d_in[9];
    const float* g3  = (const float*)d_in[10];
    const float* b3  = (const float*)d_in[11];
    const float* w4  = (const float*)d_in[12];
    const float* g4  = (const float*)d_in[13];
    const float* b4  = (const float*)d_in[14];
    const float* l1w = (const float*)d_in[15];
    const float* l1b = (const float*)d_in[16];
    const float* l2w = (const float*)d_in[17];
    const float* l2b = (const float*)d_in[18];

    float* feat = (float*)d_out;
    float* oPR  = feat + OFF_PREAL;
    float* oRC  = feat + OFF_PRECON;
    float* oWA  = feat + OFF_WA;
    float* oWP  = feat + OFF_WP;

    // ws: f2 [0,64MB), f3 [64MB,192MB), f1 [128MB,160MB) (inside f3, dead before conv3)
    char* wsb = (char*)d_ws;
    u16* f2b = (u16*)wsb;
    u16* f3b = (u16*)(wsb + 67108864L);
    u16* f1b = (u16*)(wsb + 134217728L);

    // raw f4 bf16 NCHW: elems [0,RAW_SPLIT) in top of feat region; rest in f2 region
    u16* rawlo = (u16*)d_out + 167772160L;    // byte offset 335544320
    u16* rawhi = f2b;                          // f2 dead during conv4

    // scratch inside d_out regions only written by the final kernels
    u16* Wt2 = (u16*)oWA;
    u16* Wt3 = Wt2 + 18432;
    u16* Wt4 = Wt3 + 73728;
    float* part = oWP;                                   // 4096*256*2 floats max
    float* ss1 = oRC, *ss2 = oRC + 64, *ss3 = oRC + 192, *ss4 = oRC + 448;

    prep_w<<<72,   256, 0, stream>>>(w2, Wt2, 64, 32);
    prep_w<<<288,  256, 0, stream>>>(w3, Wt3, 128, 64);
    prep_w<<<1152, 256, 0, stream>>>(w4, Wt4, 256, 128);

    conv1_direct<<<dim3(256,8), 256, 0, stream>>>(x, w1, f1b);
    bn_stats_nhwc<32><<<1024, 256, 0, stream>>>(f1b, part);
    bn_stats_final2<<<32, 256, 0, stream>>>(part, g1, b1, 32, 1024, ss1);
    bn_apply<32><<<8192, 256, 0, stream>>>(f1b, ss1, 2097152L);

    conv_mfma<32,64,false><<<dim3(256,8), 512, 0, stream>>>(f1b, Wt2, f2b, nullptr, part);
    bn_stats_final2<<<64, 256, 0, stream>>>(part, g2, b2, 64, 4096, ss2);
    bn_apply<64><<<16384, 256, 0, stream>>>(f2b, ss2, 4194304L);

    conv_mfma<64,128,false><<<dim3(256,8), 512, 0, stream>>>(f2b, Wt3, f3b, nullptr, part);
    bn_stats_final2<<<128, 256, 0, stream>>>(part, g3, b3, 128, 4096, ss3);
    bn_apply<128><<<32768, 256, 0, stream>>>(f3b, ss3, 8388608L);

    conv_mfma<128,256,true><<<dim3(256,8), 512, 0, stream>>>(f3b, Wt4, rawlo, rawhi, part);
    bn_stats_final2<<<256, 256, 0, stream>>>(part, g4, b4, 256, 4096, ss4);

    // expand raw -> fp32 feat.  Safety by launch order:
    //  e1: i in [0, 83886080)         writes feat bytes [0, 335.5MB)   (below rawlo)
    //  e2: i in [83886080, RAW_SPLIT) writes [335.5, 402.7MB) — clobbers only e1's raw
    //  e3: i in [RAW_SPLIT, 134M)     reads ws, writes [402.7, 536.9MB) — clobbers e1/e2 raw
    bn_expand<<<40960, 256, 0, stream>>>(rawlo,              ss4, feat, 0L,         83886080L);
    bn_expand<<<8192,  256, 0, stream>>>(rawlo + 83886080L,  ss4, feat, 83886080L,  16777216L);
    bn_expand<<<16384, 256, 0, stream>>>(rawhi,              ss4, feat, RAW_SPLIT,  33554432L);

    gather_w<<<8192, 256, 0, stream>>>(feat, anc, oWA);
    gather_w<<<8192, 256, 0, stream>>>(feat, pos, oWP);
    gather_patch<<<4704, 256, 0, stream>>>(x, anc, oPR);
    mlp<<<8192, 256, 0, stream>>>(oWA, l1w, l1b, l2w, l2b, oRC);
}